// Round 13
// baseline (131.151 us; speedup 1.0000x reference)
//
#include <hip/hip_runtime.h>
#include <hip/hip_bf16.h>

#define NN 8192
#define FIN 128
#define FOUT 64
#define NWRD (NN / 64)       // 128 u64 words per mask row
#define NB (NN / 8)          // 1024 mask bytes per row

typedef __attribute__((ext_vector_type(8))) short short8;
typedef __attribute__((ext_vector_type(16))) float f32x16;
typedef unsigned int u32;
typedef unsigned char u8;
typedef unsigned long long u64;

static __device__ __forceinline__ short f2bf(float f) {
    union { __hip_bfloat16 h; short s; } u;
    u.h = __float2bfloat16(f);
    return u.s;
}

// one mask byte (8 bits) -> 8 bf16 {0,1.0} packed in short8
static __device__ __forceinline__ short8 expand8(u32 b) {
    u32 xl = ((b & 0xFu) * 0x00204081u) & 0x01010101u;
    u32 xh = (((b >> 4) & 0xFu) * 0x00204081u) & 0x01010101u;
    u32 d0 = __builtin_amdgcn_perm(0u, xl, 0x0C010C00u) * 0x3F80u;
    u32 d1 = __builtin_amdgcn_perm(0u, xl, 0x0C030C02u) * 0x3F80u;
    u32 d2 = __builtin_amdgcn_perm(0u, xh, 0x0C010C00u) * 0x3F80u;
    u32 d3 = __builtin_amdgcn_perm(0u, xh, 0x0C030C02u) * 0x3F80u;
    union { u32 u[4]; short8 v; } r;
    r.u[0] = d0; r.u[1] = d1; r.u[2] = d2; r.u[3] = d3;
    return r.v;
}

// pack 8 fp32 {0,1} -> mask byte
static __device__ __forceinline__ u32 pack8(float4 a, float4 b) {
    u32 x0 = __float_as_uint(a.x), x1 = __float_as_uint(a.y);
    u32 x2 = __float_as_uint(a.z), x3 = __float_as_uint(a.w);
    u32 x4 = __float_as_uint(b.x), x5 = __float_as_uint(b.y);
    u32 x6 = __float_as_uint(b.z), x7 = __float_as_uint(b.w);
    u32 ylo = __builtin_amdgcn_perm(x1, x0, 0x0C0C0703u) |
              __builtin_amdgcn_perm(x3, x2, 0x07030C0Cu);
    u32 yhi = __builtin_amdgcn_perm(x5, x4, 0x0C0C0703u) |
              __builtin_amdgcn_perm(x7, x6, 0x07030C0Cu);
    u32 nlo = (((ylo >> 5) & 0x01010101u) * 0x01020408u) >> 24;
    u32 nhi = (((yhi >> 5) & 0x01010101u) * 0x01020408u) >> 24;
    return nlo | (nhi << 4);
}

// ---------- XW (no bias) -> fragment-major bf16 + y = XW@phi_j + cb ----------
__global__ __launch_bounds__(256) void xw_kernel(const float* __restrict__ X,
        const float* __restrict__ W, const float* __restrict__ bias,
        const float* __restrict__ phi, short* __restrict__ XWf,
        float* __restrict__ y, float* __restrict__ cb) {
    __shared__ float Xs[64][FIN + 1];
    __shared__ short T[64][72];
    __shared__ float yp[4][64];
    const int t = threadIdx.x;
    const int jb = blockIdx.x * 64;
    for (int u = t; u < 64 * FIN; u += 256) {
        int r = u >> 7, k = u & (FIN - 1);
        Xs[r][k] = X[(size_t)(jb + r) * FIN + k];
    }
    __syncthreads();
    const int j = t & 63;
    const int cg = t >> 6;
    float acc[16] = {};
    for (int k = 0; k < FIN; ++k) {
        float x = Xs[j][k];
        #pragma unroll
        for (int q = 0; q < 16; ++q)
            acc[q] = fmaf(x, W[k * FOUT + cg * 16 + q], acc[q]);
    }
    float ys = 0.f;
    union { short s[16]; short8 v[2]; } pk;
    #pragma unroll
    for (int q = 0; q < 16; ++q) {
        ys = fmaf(acc[q], phi[FOUT + cg * 16 + q], ys);
        pk.s[q] = f2bf(acc[q]);
    }
    *(short8*)&T[j][cg * 16] = pk.v[0];
    *(short8*)&T[j][cg * 16 + 8] = pk.v[1];
    yp[cg][j] = ys;
    __syncthreads();
    if (t < 64) y[jb + t] = yp[0][t] + yp[1][t] + yp[2][t] + yp[3][t];
    if (blockIdx.x == 0 && t == 0) {
        float s = 0.f;
        for (int c = 0; c < FOUT; ++c) s = fmaf(bias[c], phi[FOUT + c], s);
        cb[0] = s;
    }
    #pragma unroll
    for (int uu = 0; uu < 2; ++uu) {
        int u = t + uu * 256;
        int f = u >> 6, ln = u & 63;
        int c = (f & 1) * 32 + (ln & 31);
        int j0 = (f >> 1) * 16 + (ln >> 5) * 8;
        union { short s[8]; short8 v; } w8;
        #pragma unroll
        for (int e = 0; e < 8; ++e) w8.s[e] = T[j0 + e][c];
        size_t fg = ((size_t)(jb >> 4) + (f >> 1)) * 2 + (f & 1);
        *(short8*)&XWf[fg * 512 + ln * 8] = w8.v;
    }
}

// ---------- FUSED stream: A -> mask bits + exact sj + mm1 (agg = mask@XW) ----------
// 256 blocks x 512 thr (8 waves) own 32 rows x full K. Per 1024-chunk:
// pack phase (HBM stream) -> barrier -> MFMA phase (LDS bits + L2 B-frags).
__global__ __launch_bounds__(512, 4) void stream_kernel(const float* __restrict__ A,
        const float* __restrict__ y, const float* __restrict__ cb,
        const short* __restrict__ XWf, u8* __restrict__ m8,
        float* __restrict__ sjv, float* __restrict__ maxp,
        float* __restrict__ aggr) {
    __shared__ union {
        struct { float4 ys4[2048]; u8 bits[2][32][132]; } s;   // 32KB + 8.25KB
        float red[8][2048];                                    // 64KB
    } sm;
    __shared__ float smax[8];
    const int t = threadIdx.x;
    const int w = t >> 6, l = t & 63;
    const int brow = blockIdx.x * 32;

    for (int i = t; i < 2048; i += 512)
        sm.s.ys4[i ^ ((i >> 3) & 7)] = ((const float4*)y)[i];
    __syncthreads();

    float sacc[4] = {};
    f32x16 acc0 = {}, acc1 = {};
    const int kh = l >> 5;

    for (int kc = 0; kc < 8; ++kc) {
        u8* bb = &sm.s.bits[kc & 1][0][0];
        // ---- pack phase: wave w owns rows brow + w*4 .. +3 ----
        #pragma unroll
        for (int seg = 0; seg < 2; ++seg) {
            const int f0 = kc * 256 + seg * 128 + l * 2;
            const int sw = (f0 >> 3) & 7;      // uniform for f0, f0+1
            float4 y0 = sm.s.ys4[f0 ^ sw];
            float4 y1 = sm.s.ys4[(f0 + 1) ^ sw];
            #pragma unroll
            for (int rr = 0; rr < 4; ++rr) {
                const int row = brow + w * 4 + rr;
                const float4* ap = (const float4*)(A + (size_t)row * NN
                                                   + kc * 1024 + seg * 512 + l * 8);
                float4 a = ap[0];
                float4 b = ap[1];
                float sv = sacc[rr];
                sv = fmaf(a.x, y0.x, sv); sv = fmaf(a.y, y0.y, sv);
                sv = fmaf(a.z, y0.z, sv); sv = fmaf(a.w, y0.w, sv);
                sv = fmaf(b.x, y1.x, sv); sv = fmaf(b.y, y1.y, sv);
                sv = fmaf(b.z, y1.z, sv); sv = fmaf(b.w, y1.w, sv);
                sacc[rr] = sv;
                u32 byte = pack8(a, b);
                bb[(w * 4 + rr) * 132 + seg * 64 + l] = (u8)byte;
                m8[(size_t)row * NB + kc * 128 + seg * 64 + l] = (u8)byte;
            }
        }
        __syncthreads();
        // ---- MFMA phase: wave w covers k = kc*1024 + w*128 + kt*16 ----
        #pragma unroll
        for (int kt = 0; kt < 8; ++kt) {
            u32 bby = bb[(l & 31) * 132 + w * 16 + kt * 2 + kh];
            const short* bp = XWf + ((size_t)(kc * 64 + w * 8 + kt)) * 1024 + l * 8;
            short8 bf0 = *(const short8*)(bp);
            short8 bf1 = *(const short8*)(bp + 512);
            short8 a = expand8(bby);
            acc0 = __builtin_amdgcn_mfma_f32_32x32x16_bf16(a, bf0, acc0, 0, 0, 0);
            acc1 = __builtin_amdgcn_mfma_f32_32x32x16_bf16(a, bf1, acc1, 0, 0, 0);
        }
        // next pack writes the other bits buffer; no second barrier needed
    }

    // ---- sj reduce + block max ----
    const float cbv = cb[0];
    float wmax = -3.0e38f;
    #pragma unroll
    for (int rr = 0; rr < 4; ++rr) {
        float sv = sacc[rr];
        #pragma unroll
        for (int o = 32; o >= 1; o >>= 1) sv += __shfl_down(sv, o, 64);
        if (l == 0) {
            float sj = sv + cbv;
            sjv[brow + w * 4 + rr] = sj;
            wmax = fmaxf(wmax, sj);
        }
    }
    if (l == 0) smax[w] = wmax;
    __syncthreads();   // bits/ys4 reads done; smax written -> safe to reuse union
    if (t == 0) {
        float bm = smax[0];
        #pragma unroll
        for (int q = 1; q < 8; ++q) bm = fmaxf(bm, smax[q]);
        maxp[blockIdx.x] = bm;
    }

    // ---- cross-wave K-reduce of acc in LDS -> aggr ----
    const int cc = l & 31;
    const int rq4 = 4 * kh;
    #pragma unroll
    for (int q = 0; q < 16; ++q) {
        int row = (q & 3) + 8 * (q >> 2) + rq4;
        sm.red[w][row * 64 + cc] = acc0[q];
        sm.red[w][row * 64 + 32 + cc] = acc1[q];
    }
    __syncthreads();
    float4 s = {0.f, 0.f, 0.f, 0.f};
    #pragma unroll
    for (int ww = 0; ww < 8; ++ww) {
        float4 v = *(const float4*)&sm.red[ww][t * 4];
        s.x += v.x; s.y += v.y; s.z += v.z; s.w += v.w;
    }
    *(float4*)&aggr[(size_t)brow * 64 + t * 4] = s;
}

__global__ __launch_bounds__(256) void maxfin_kernel(const float* __restrict__ maxp,
                                                     float* __restrict__ Mb) {
    float m = maxp[threadIdx.x];
    #pragma unroll
    for (int o = 32; o >= 1; o >>= 1) m = fmaxf(m, __shfl_down(m, o, 64));
    __shared__ float red[4];
    if ((threadIdx.x & 63) == 0) red[threadIdx.x >> 6] = m;
    __syncthreads();
    if (threadIdx.x == 0)
        Mb[0] = fmaxf(fmaxf(red[0], red[1]), fmaxf(red[2], red[3]));
}

// ---------- (mask+I) @ B2 with fused relu(h/den) epilogue ----------
template <bool DIAG, bool EPI>
__global__ __launch_bounds__(512) void mm_kernel(const u64* __restrict__ mask,
        const short* __restrict__ Bfrag, const float* __restrict__ den,
        float* __restrict__ outv) {
    __shared__ float red[8][2048];
    const int t = threadIdx.x;
    const int w = t >> 6;
    const int l = t & 63;
    const int brow = blockIdx.x * 32;
    const int r0 = brow + (l & 31);
    const int kh = l >> 5;
    const int k0 = w * 1024;

    const u64* mp = mask + (size_t)r0 * NWRD + (k0 >> 6);
    u64 mw[16];
    #pragma unroll
    for (int q = 0; q < 16; ++q) mw[q] = mp[q];

    f32x16 acc0 = {}, acc1 = {};
    const short* bp = Bfrag + (size_t)(k0 >> 4) * 2 * 512 + l * 8;

    short8 f0a, f1a, f0b, f1b, f0c, f1c, f0d, f1d;
    f0a = *(const short8*)(bp + 0 * 512);  f1a = *(const short8*)(bp + 1 * 512);
    f0b = *(const short8*)(bp + 2 * 512);  f1b = *(const short8*)(bp + 3 * 512);
    f0c = *(const short8*)(bp + 4 * 512);  f1c = *(const short8*)(bp + 5 * 512);
    f0d = *(const short8*)(bp + 6 * 512);  f1d = *(const short8*)(bp + 7 * 512);

    #pragma unroll
    for (int kt4 = 0; kt4 < 16; ++kt4) {
        #pragma unroll
        for (int pp = 0; pp < 4; ++pp) {
            const int kt = kt4 * 4 + pp;
            const int bidx = kt * 2 + kh;
            u32 b = (u32)(mw[bidx >> 3] >> ((bidx & 7) * 8)) & 0xFFu;
            if (DIAG) {
                u32 d = (u32)(r0 - (k0 + kt * 16 + kh * 8));
                if (d < 8u) b |= 1u << d;
            }
            short8 a = expand8(b);
            short8 bf0 = (pp == 0) ? f0a : (pp == 1) ? f0b : (pp == 2) ? f0c : f0d;
            short8 bf1 = (pp == 0) ? f1a : (pp == 1) ? f1b : (pp == 2) ? f1c : f1d;
            acc0 = __builtin_amdgcn_mfma_f32_32x32x16_bf16(a, bf0, acc0, 0, 0, 0);
            acc1 = __builtin_amdgcn_mfma_f32_32x32x16_bf16(a, bf1, acc1, 0, 0, 0);
            if (kt + 4 < 64) {
                short8 n0 = *(const short8*)(bp + ((kt + 4) * 2 + 0) * 512);
                short8 n1 = *(const short8*)(bp + ((kt + 4) * 2 + 1) * 512);
                if (pp == 0) { f0a = n0; f1a = n1; }
                else if (pp == 1) { f0b = n0; f1b = n1; }
                else if (pp == 2) { f0c = n0; f1c = n1; }
                else { f0d = n0; f1d = n1; }
            }
        }
    }

    const int cc = l & 31;
    const int rq4 = 4 * (l >> 5);
    #pragma unroll
    for (int q = 0; q < 16; ++q) {
        int row = (q & 3) + 8 * (q >> 2) + rq4;
        red[w][row * 64 + cc] = acc0[q];
        red[w][row * 64 + 32 + cc] = acc1[q];
    }
    __syncthreads();
    float4 s = {0.f, 0.f, 0.f, 0.f};
    #pragma unroll
    for (int ww = 0; ww < 8; ++ww) {
        float4 v = *(const float4*)&red[ww][t * 4];
        s.x += v.x; s.y += v.y; s.z += v.z; s.w += v.w;
    }
    if (EPI) {
        const float d = den[brow + (t >> 4)];
        s.x /= d; s.y /= d; s.z /= d; s.w /= d;
        s.x = s.x > 0.f ? s.x : 0.f;
        s.y = s.y > 0.f ? s.y : 0.f;
        s.z = s.z > 0.f ? s.z : 0.f;
        s.w = s.w > 0.f ? s.w : 0.f;
    }
    *(float4*)&outv[(size_t)brow * 64 + t * 4] = s;
}

// ---------- fused: bbuild (blocks 0..127) | den (blocks 128..639) ----------
__global__ __launch_bounds__(256) void ph3_kernel(const float* __restrict__ aggr,
        const float* __restrict__ bias, const float* __restrict__ sjv,
        const float* __restrict__ Mb, short* __restrict__ B2f,
        const u64* __restrict__ mask, float* __restrict__ den) {
    __shared__ union { short Tt[64][72]; float es[NN]; } sm;
    const int b = blockIdx.x, t = threadIdx.x;
    if (b < 128) {
        const int jb = b * 64;
        const int jl = t >> 2;
        const int j = jb + jl;
        const int cg = (t & 3) * 16;
        const float4* p = (const float4*)&aggr[(size_t)j * 64 + cg];
        float4 q0 = p[0], q1 = p[1], q2 = p[2], q3 = p[3];
        float v[16] = {q0.x, q0.y, q0.z, q0.w, q1.x, q1.y, q1.z, q1.w,
                       q2.x, q2.y, q2.z, q2.w, q3.x, q3.y, q3.z, q3.w};
        const float e = __expf(sjv[j] - Mb[0]);
        union { short s[16]; short8 w[2]; } pk;
        #pragma unroll
        for (int q = 0; q < 16; ++q) pk.s[q] = f2bf((v[q] + bias[cg + q]) * e);
        *(short8*)&sm.Tt[jl][cg] = pk.w[0];
        *(short8*)&sm.Tt[jl][cg + 8] = pk.w[1];
        __syncthreads();
        #pragma unroll
        for (int uu = 0; uu < 2; ++uu) {
            int u = t + uu * 256;
            int f = u >> 6, ln = u & 63;
            int c = (f & 1) * 32 + (ln & 31);
            int j0 = (f >> 1) * 16 + (ln >> 5) * 8;
            union { short s[8]; short8 v; } w8;
            #pragma unroll
            for (int e8 = 0; e8 < 8; ++e8) w8.s[e8] = sm.Tt[j0 + e8][c];
            size_t fg = ((size_t)(jb >> 4) + (f >> 1)) * 2 + (f & 1);
            *(short8*)&B2f[fg * 512 + ln * 8] = w8.v;
        }
    } else {
        const float M = Mb[0];
        for (int i = t; i < NN; i += 256)
            sm.es[i ^ ((i >> 9) & 31)] = __expf(sjv[i] - M);
        __syncthreads();
        const float* es = sm.es;
        const int row = (b - 128) * 16 + (t >> 4);
        const int cs = t & 15;
        const u64* mp = mask + (size_t)row * NWRD + cs * 8;
        float s = 0.f;
        #pragma unroll
        for (int wd = 0; wd < 8; ++wd) {
            u64 mwv = mp[wd];
            const int kg = cs * 512 + wd * 64;
            u32 d = (u32)(row - kg);
            if (d < 64u) mwv |= 1ull << d;     // +I
            #pragma unroll
            for (int b8 = 0; b8 < 8; ++b8) {
                u32 by = (u32)(mwv >> (b8 * 8)) & 0xFFu;
                u32 xl = ((by & 0xFu) * 0x00204081u) & 0x01010101u;
                u32 xh = (((by >> 4) & 0xFu) * 0x00204081u) & 0x01010101u;
                u32 d0 = __builtin_amdgcn_perm(0u, xl, 0x0C010C00u) * 0x3F80u;
                u32 d1 = __builtin_amdgcn_perm(0u, xl, 0x0C030C02u) * 0x3F80u;
                u32 d2 = __builtin_amdgcn_perm(0u, xh, 0x0C010C00u) * 0x3F80u;
                u32 d3 = __builtin_amdgcn_perm(0u, xh, 0x0C030C02u) * 0x3F80u;
                const int base = kg + b8 * 8;   // (base>>9)&31 == cs
                s = fmaf(__uint_as_float(d0 << 16),          es[(base + 0) ^ cs], s);
                s = fmaf(__uint_as_float(d0 & 0xFFFF0000u),  es[(base + 1) ^ cs], s);
                s = fmaf(__uint_as_float(d1 << 16),          es[(base + 2) ^ cs], s);
                s = fmaf(__uint_as_float(d1 & 0xFFFF0000u),  es[(base + 3) ^ cs], s);
                s = fmaf(__uint_as_float(d2 << 16),          es[(base + 4) ^ cs], s);
                s = fmaf(__uint_as_float(d2 & 0xFFFF0000u),  es[(base + 5) ^ cs], s);
                s = fmaf(__uint_as_float(d3 << 16),          es[(base + 6) ^ cs], s);
                s = fmaf(__uint_as_float(d3 & 0xFFFF0000u),  es[(base + 7) ^ cs], s);
            }
        }
        #pragma unroll
        for (int o = 8; o >= 1; o >>= 1) s += __shfl_xor(s, o, 64);
        if (cs == 0) den[row] = s;
    }
}

extern "C" void kernel_launch(void* const* d_in, const int* in_sizes, int n_in,
                              void* d_out, int out_size, void* d_ws, size_t ws_size,
                              hipStream_t stream) {
    const float* A    = (const float*)d_in[0];
    const float* X    = (const float*)d_in[1];
    const float* W    = (const float*)d_in[2];
    const float* bias = (const float*)d_in[3];
    const float* phi  = (const float*)d_in[4];
    float* out = (float*)d_out;

    char* ws = (char*)d_ws;
    size_t off = 0;
    auto alloc = [&](size_t bytes) -> void* {
        void* p = ws + off;
        off += (bytes + 255) & ~(size_t)255;
        return p;
    };
    u8*    m8   = (u8*)alloc((size_t)NN * NB);
    short* XWf  = (short*)alloc((size_t)FOUT * NN * 2);
    float* y    = (float*)alloc((size_t)NN * 4);
    float* cb   = (float*)alloc(256);
    float* sjv  = (float*)alloc((size_t)NN * 4);
    float* maxp = (float*)alloc(256 * 4);
    float* Mb   = (float*)alloc(256);
    float* aggr = (float*)alloc((size_t)NN * FOUT * 4);
    short* B2f  = (short*)alloc((size_t)FOUT * NN * 2);
    float* den  = (float*)alloc((size_t)NN * 4);

    xw_kernel<<<NN / 64, 256, 0, stream>>>(X, W, bias, phi, XWf, y, cb);
    stream_kernel<<<NN / 32, 512, 0, stream>>>(A, y, cb, XWf, m8, sjv, maxp, aggr);
    maxfin_kernel<<<1, 256, 0, stream>>>(maxp, Mb);
    ph3_kernel<<<640, 256, 0, stream>>>(aggr, bias, sjv, Mb, B2f, (const u64*)m8, den);
    mm_kernel<true, true><<<NN / 32, 512, 0, stream>>>(
        (const u64*)m8, B2f, den, out);
}

// Round 14
// 127.132 us; speedup vs baseline: 1.0316x; 1.0316x over previous
//
#include <hip/hip_runtime.h>
#include <hip/hip_bf16.h>

#define NN 8192
#define FIN 128
#define FOUT 64
#define NWRD (NN / 64)       // 128 u64 words per mask row
#define NB (NN / 8)          // 1024 mask bytes per row

typedef __attribute__((ext_vector_type(8))) short short8;
typedef __attribute__((ext_vector_type(16))) float f32x16;
typedef unsigned int u32;
typedef unsigned char u8;
typedef unsigned long long u64;

static __device__ __forceinline__ short f2bf(float f) {
    union { __hip_bfloat16 h; short s; } u;
    u.h = __float2bfloat16(f);
    return u.s;
}

// one mask byte (8 bits) -> 8 bf16 {0,1.0} packed in short8
static __device__ __forceinline__ short8 expand8(u32 b) {
    u32 xl = ((b & 0xFu) * 0x00204081u) & 0x01010101u;
    u32 xh = (((b >> 4) & 0xFu) * 0x00204081u) & 0x01010101u;
    u32 d0 = __builtin_amdgcn_perm(0u, xl, 0x0C010C00u) * 0x3F80u;
    u32 d1 = __builtin_amdgcn_perm(0u, xl, 0x0C030C02u) * 0x3F80u;
    u32 d2 = __builtin_amdgcn_perm(0u, xh, 0x0C010C00u) * 0x3F80u;
    u32 d3 = __builtin_amdgcn_perm(0u, xh, 0x0C030C02u) * 0x3F80u;
    union { u32 u[4]; short8 v; } r;
    r.u[0] = d0; r.u[1] = d1; r.u[2] = d2; r.u[3] = d3;
    return r.v;
}

// ---------- XW (no bias) -> fragment-major bf16 + y = XW@phi_j + cb ----------
__global__ __launch_bounds__(256) void xw_kernel(const float* __restrict__ X,
        const float* __restrict__ W, const float* __restrict__ bias,
        const float* __restrict__ phi, short* __restrict__ XWf,
        float* __restrict__ y, float* __restrict__ cb) {
    __shared__ float Xs[64][FIN + 1];
    __shared__ short T[64][72];     // [node j][col c] bf16, padded
    __shared__ float yp[4][64];
    const int t = threadIdx.x;
    const int jb = blockIdx.x * 64;
    for (int u = t; u < 64 * FIN; u += 256) {
        int r = u >> 7, k = u & (FIN - 1);
        Xs[r][k] = X[(size_t)(jb + r) * FIN + k];
    }
    __syncthreads();
    const int j = t & 63;
    const int cg = t >> 6;
    float acc[16] = {};
    for (int k = 0; k < FIN; ++k) {
        float x = Xs[j][k];
        #pragma unroll
        for (int q = 0; q < 16; ++q)
            acc[q] = fmaf(x, W[k * FOUT + cg * 16 + q], acc[q]);
    }
    float ys = 0.f;
    union { short s[16]; short8 v[2]; } pk;
    #pragma unroll
    for (int q = 0; q < 16; ++q) {
        ys = fmaf(acc[q], phi[FOUT + cg * 16 + q], ys);
        pk.s[q] = f2bf(acc[q]);
    }
    *(short8*)&T[j][cg * 16] = pk.v[0];
    *(short8*)&T[j][cg * 16 + 8] = pk.v[1];
    yp[cg][j] = ys;
    __syncthreads();
    if (t < 64) y[jb + t] = yp[0][t] + yp[1][t] + yp[2][t] + yp[3][t];
    if (blockIdx.x == 0 && t == 0) {
        float s = 0.f;
        for (int c = 0; c < FOUT; ++c) s = fmaf(bias[c], phi[FOUT + c], s);
        cb[0] = s;
    }
    // fragment-major: frag fi = ktile*2 + colgroup; lane l: B[k=(l>>5)*8+e][c=(l&31)]
    #pragma unroll
    for (int uu = 0; uu < 2; ++uu) {
        int u = t + uu * 256;
        int f = u >> 6, ln = u & 63;
        int c = (f & 1) * 32 + (ln & 31);
        int j0 = (f >> 1) * 16 + (ln >> 5) * 8;
        union { short s[8]; short8 v; } w8;
        #pragma unroll
        for (int e = 0; e < 8; ++e) w8.s[e] = T[j0 + e][c];
        size_t fg = ((size_t)(jb >> 4) + (f >> 1)) * 2 + (f & 1);
        *(short8*)&XWf[fg * 512 + ln * 8] = w8.v;
    }
}

// ---------- A -> bitmask bytes; fused exact sj_i = A@y + cb; block max ----------
// y staged in LDS with XOR-swizzled float4 index (kills 16-way bank conflict).
__global__ __launch_bounds__(256) void mask_kernel(const float* __restrict__ A,
        const float* __restrict__ y, const float* __restrict__ cb,
        u8* __restrict__ m8, float* __restrict__ sjv, float* __restrict__ maxp) {
    __shared__ float4 ys4[NN / 4];
    for (int i = threadIdx.x; i < NN / 4; i += 256)
        ys4[i ^ ((i >> 3) & 7)] = ((const float4*)y)[i];
    __syncthreads();
    const int t = threadIdx.x;
    const int row = blockIdx.x * 4 + (t >> 6);
    const int l = t & 63;
    const float* ar = A + (size_t)row * NN + l * 8;
    u8* mr = m8 + (size_t)row * NB + l;
    float s = 0.f;
    #pragma unroll 2
    for (int kc = 0; kc < NN; kc += 512) {
        float4 a = *(const float4*)(ar + kc);
        float4 b = *(const float4*)(ar + kc + 4);
        const int f0 = (kc >> 2) + l * 2;
        const int sw = (f0 >> 3) & 7;       // same for f0 and f0+1 (f0 even)
        float4 y0 = ys4[f0 ^ sw];
        float4 y1 = ys4[(f0 + 1) ^ sw];
        s = fmaf(a.x, y0.x, s); s = fmaf(a.y, y0.y, s);
        s = fmaf(a.z, y0.z, s); s = fmaf(a.w, y0.w, s);
        s = fmaf(b.x, y1.x, s); s = fmaf(b.y, y1.y, s);
        s = fmaf(b.z, y1.z, s); s = fmaf(b.w, y1.w, s);
        u32 x0 = __float_as_uint(a.x), x1 = __float_as_uint(a.y);
        u32 x2 = __float_as_uint(a.z), x3 = __float_as_uint(a.w);
        u32 x4 = __float_as_uint(b.x), x5 = __float_as_uint(b.y);
        u32 x6 = __float_as_uint(b.z), x7 = __float_as_uint(b.w);
        u32 ylo = __builtin_amdgcn_perm(x1, x0, 0x0C0C0703u) |
                  __builtin_amdgcn_perm(x3, x2, 0x07030C0Cu);
        u32 yhi = __builtin_amdgcn_perm(x5, x4, 0x0C0C0703u) |
                  __builtin_amdgcn_perm(x7, x6, 0x07030C0Cu);
        u32 nlo = (((ylo >> 5) & 0x01010101u) * 0x01020408u) >> 24;
        u32 nhi = (((yhi >> 5) & 0x01010101u) * 0x01020408u) >> 24;
        mr[kc >> 3] = (u8)(nlo | (nhi << 4));
    }
    #pragma unroll
    for (int o = 32; o >= 1; o >>= 1) s += __shfl_down(s, o, 64);
    __shared__ float red[4];
    float sj = s + cb[0];
    if (l == 0) { sjv[row] = sj; red[t >> 6] = sj; }
    __syncthreads();
    if (t == 0)
        maxp[blockIdx.x] = fmaxf(fmaxf(red[0], red[1]), fmaxf(red[2], red[3]));
}

// ---------- mask(A[+I]) @ B : full-K, col-split (blockIdx.y = col-frag) ----------
// grid (256,2) x 512 thr; 32-KB LDS + <=128 VGPR -> 2 blocks/CU, 16 waves/CU.
// EPI: fuse out = relu(h/den) into the epilogue.
template <bool DIAG, bool EPI>
__global__ __launch_bounds__(512, 2) void mm_kernel(const u64* __restrict__ mask,
        const short* __restrict__ Bfrag, const float* __restrict__ den,
        float* __restrict__ outv) {
    __shared__ float red[8][1024];
    const int t = threadIdx.x;
    const int w = t >> 6;          // wave 0..7
    const int l = t & 63;
    const int brow = blockIdx.x * 32;
    const int cf = blockIdx.y;     // col-frag 0/1 (32 cols each)
    const int r0 = brow + (l & 31);
    const int kh = l >> 5;
    const int k0 = w * 1024;       // wave's K-chunk base

    const u64* mp = mask + (size_t)r0 * NWRD + (k0 >> 6);
    u64 mw[16];
    #pragma unroll
    for (int q = 0; q < 16; ++q) mw[q] = mp[q];

    f32x16 acc = {};
    // frag index = kt_global*2 + cf; each frag = 512 shorts
    const short* bp = Bfrag + ((size_t)(k0 >> 4) * 2 + cf) * 512 + l * 8;

    short8 fa, fb, fc, fd;
    fa = *(const short8*)(bp + 0 * 1024);
    fb = *(const short8*)(bp + 1 * 1024);
    fc = *(const short8*)(bp + 2 * 1024);
    fd = *(const short8*)(bp + 3 * 1024);

    #pragma unroll
    for (int kt4 = 0; kt4 < 16; ++kt4) {
        #pragma unroll
        for (int pp = 0; pp < 4; ++pp) {
            const int kt = kt4 * 4 + pp;
            const int bidx = kt * 2 + kh;
            u32 b = (u32)(mw[bidx >> 3] >> ((bidx & 7) * 8)) & 0xFFu;
            if (DIAG) {
                u32 d = (u32)(r0 - (k0 + kt * 16 + kh * 8));
                if (d < 8u) b |= 1u << d;
            }
            short8 a = expand8(b);
            short8 bf = (pp == 0) ? fa : (pp == 1) ? fb : (pp == 2) ? fc : fd;
            acc = __builtin_amdgcn_mfma_f32_32x32x16_bf16(a, bf, acc, 0, 0, 0);
            if (kt + 4 < 64) {
                short8 n = *(const short8*)(bp + (kt + 4) * 1024);
                if (pp == 0) fa = n;
                else if (pp == 1) fb = n;
                else if (pp == 2) fc = n;
                else fd = n;
            }
        }
    }

    // cross-wave reduce in LDS: D layout col=lane&31, row=(q&3)+8*(q>>2)+4*(lane>>5)
    const int cc = l & 31;
    const int rq4 = 4 * kh;
    #pragma unroll
    for (int q = 0; q < 16; ++q) {
        int row = (q & 3) + 8 * (q >> 2) + rq4;
        red[w][row * 32 + cc] = acc[q];
    }
    __syncthreads();
    const int x = t * 2;
    const int row = x >> 5;
    float2 s = {0.f, 0.f};
    #pragma unroll
    for (int ww = 0; ww < 8; ++ww) {
        float2 v = *(const float2*)&red[ww][x];
        s.x += v.x; s.y += v.y;
    }
    if (EPI) {
        const float d = den[brow + row];
        s.x /= d; s.y /= d;
        s.x = s.x > 0.f ? s.x : 0.f;
        s.y = s.y > 0.f ? s.y : 0.f;
    }
    *(float2*)&outv[(size_t)(brow + row) * 64 + cf * 32 + (x & 31)] = s;
}

// ---------- fused: Mb self-reduce + bbuild (0..127) | den (128..639) ----------
__global__ __launch_bounds__(256) void ph3_kernel(const float* __restrict__ aggr,
        const float* __restrict__ bias, const float* __restrict__ sjv,
        const float* __restrict__ maxp, short* __restrict__ B2f,
        const u64* __restrict__ mask, float* __restrict__ den) {
    __shared__ union { short Tt[64][72]; float es[NN]; } sm;
    __shared__ float mred[4];
    __shared__ float MbS;
    const int b = blockIdx.x, t = threadIdx.x;
    // self-reduce global max from maxp[2048] (replaces maxfin launch)
    {
        float m = maxp[t];
        #pragma unroll
        for (int i = 1; i < 8; ++i) m = fmaxf(m, maxp[t + i * 256]);
        #pragma unroll
        for (int o = 32; o >= 1; o >>= 1) m = fmaxf(m, __shfl_down(m, o, 64));
        if ((t & 63) == 0) mred[t >> 6] = m;
        __syncthreads();
        if (t == 0)
            MbS = fmaxf(fmaxf(mred[0], mred[1]), fmaxf(mred[2], mred[3]));
        __syncthreads();
    }
    const float M = MbS;
    if (b < 128) {
        // B2 = bf16(e_j * (agg_j + bias)) in fragment-major
        const int jb = b * 64;
        const int jl = t >> 2;
        const int j = jb + jl;
        const int cg = (t & 3) * 16;
        const float4* p = (const float4*)&aggr[(size_t)j * 64 + cg];
        float4 q0 = p[0], q1 = p[1], q2 = p[2], q3 = p[3];
        float v[16] = {q0.x, q0.y, q0.z, q0.w, q1.x, q1.y, q1.z, q1.w,
                       q2.x, q2.y, q2.z, q2.w, q3.x, q3.y, q3.z, q3.w};
        const float e = __expf(sjv[j] - M);
        union { short s[16]; short8 w[2]; } pk;
        #pragma unroll
        for (int q = 0; q < 16; ++q) pk.s[q] = f2bf((v[q] + bias[cg + q]) * e);
        *(short8*)&sm.Tt[jl][cg] = pk.w[0];
        *(short8*)&sm.Tt[jl][cg + 8] = pk.w[1];
        __syncthreads();
        #pragma unroll
        for (int uu = 0; uu < 2; ++uu) {
            int u = t + uu * 256;
            int f = u >> 6, ln = u & 63;
            int c = (f & 1) * 32 + (ln & 31);
            int j0 = (f >> 1) * 16 + (ln >> 5) * 8;
            union { short s[8]; short8 v; } w8;
            #pragma unroll
            for (int e8 = 0; e8 < 8; ++e8) w8.s[e8] = sm.Tt[j0 + e8][c];
            size_t fg = ((size_t)(jb >> 4) + (f >> 1)) * 2 + (f & 1);
            *(short8*)&B2f[fg * 512 + ln * 8] = w8.v;
        }
    } else {
        // den_i = sum_{j in mask+I} e_j  (swizzled es: idx ^ ((idx>>9)&31))
        for (int i = t; i < NN; i += 256)
            sm.es[i ^ ((i >> 9) & 31)] = __expf(sjv[i] - M);
        __syncthreads();
        const float* es = sm.es;
        const int row = (b - 128) * 16 + (t >> 4);
        const int cs = t & 15;
        const u64* mp = mask + (size_t)row * NWRD + cs * 8;
        float s = 0.f;
        #pragma unroll
        for (int wd = 0; wd < 8; ++wd) {
            u64 mwv = mp[wd];
            const int kg = cs * 512 + wd * 64;
            u32 d = (u32)(row - kg);
            if (d < 64u) mwv |= 1ull << d;     // +I
            #pragma unroll
            for (int b8 = 0; b8 < 8; ++b8) {
                u32 by = (u32)(mwv >> (b8 * 8)) & 0xFFu;
                u32 xl = ((by & 0xFu) * 0x00204081u) & 0x01010101u;
                u32 xh = (((by >> 4) & 0xFu) * 0x00204081u) & 0x01010101u;
                u32 d0 = __builtin_amdgcn_perm(0u, xl, 0x0C010C00u) * 0x3F80u;
                u32 d1 = __builtin_amdgcn_perm(0u, xl, 0x0C030C02u) * 0x3F80u;
                u32 d2 = __builtin_amdgcn_perm(0u, xh, 0x0C010C00u) * 0x3F80u;
                u32 d3 = __builtin_amdgcn_perm(0u, xh, 0x0C030C02u) * 0x3F80u;
                const int base = kg + b8 * 8;   // (base>>9)&31 == cs
                s = fmaf(__uint_as_float(d0 << 16),          es[(base + 0) ^ cs], s);
                s = fmaf(__uint_as_float(d0 & 0xFFFF0000u),  es[(base + 1) ^ cs], s);
                s = fmaf(__uint_as_float(d1 << 16),          es[(base + 2) ^ cs], s);
                s = fmaf(__uint_as_float(d1 & 0xFFFF0000u),  es[(base + 3) ^ cs], s);
                s = fmaf(__uint_as_float(d2 << 16),          es[(base + 4) ^ cs], s);
                s = fmaf(__uint_as_float(d2 & 0xFFFF0000u),  es[(base + 5) ^ cs], s);
                s = fmaf(__uint_as_float(d3 << 16),          es[(base + 6) ^ cs], s);
                s = fmaf(__uint_as_float(d3 & 0xFFFF0000u),  es[(base + 7) ^ cs], s);
            }
        }
        #pragma unroll
        for (int o = 8; o >= 1; o >>= 1) s += __shfl_xor(s, o, 64);
        if (cs == 0) den[row] = s;
    }
}

extern "C" void kernel_launch(void* const* d_in, const int* in_sizes, int n_in,
                              void* d_out, int out_size, void* d_ws, size_t ws_size,
                              hipStream_t stream) {
    const float* A    = (const float*)d_in[0];
    const float* X    = (const float*)d_in[1];
    const float* W    = (const float*)d_in[2];
    const float* bias = (const float*)d_in[3];
    const float* phi  = (const float*)d_in[4];
    float* out = (float*)d_out;

    char* ws = (char*)d_ws;
    size_t off = 0;
    auto alloc = [&](size_t bytes) -> void* {
        void* p = ws + off;
        off += (bytes + 255) & ~(size_t)255;
        return p;
    };
    u8*    m8   = (u8*)alloc((size_t)NN * NB);
    short* XWf  = (short*)alloc((size_t)FOUT * NN * 2);
    float* y    = (float*)alloc((size_t)NN * 4);
    float* cb   = (float*)alloc(256);
    float* sjv  = (float*)alloc((size_t)NN * 4);
    float* maxp = (float*)alloc(2048 * 4);
    float* aggr = (float*)alloc((size_t)NN * FOUT * 4);
    short* B2f  = (short*)alloc((size_t)FOUT * NN * 2);
    float* den  = (float*)alloc((size_t)NN * 4);

    xw_kernel<<<NN / 64, 256, 0, stream>>>(X, W, bias, phi, XWf, y, cb);
    mask_kernel<<<NN / 4, 256, 0, stream>>>(A, y, cb, m8, sjv, maxp);
    mm_kernel<false, false><<<dim3(NN / 32, 2), 512, 0, stream>>>(
        (const u64*)m8, XWf, nullptr, aggr);
    ph3_kernel<<<640, 256, 0, stream>>>(aggr, bias, sjv, maxp, B2f,
                                        (const u64*)m8, den);
    mm_kernel<true, true><<<dim3(NN / 32, 2), 512, 0, stream>>>(
        (const u64*)m8, B2f, den, out);
}